// Round 5
// baseline (375.582 us; speedup 1.0000x reference)
//
#include <hip/hip_runtime.h>
#include <hip/hip_fp16.h>

// Problem constants
#define B_   128
#define N_   68
#define C_   3
#define P_   32
#define K_   16
#define FD_  64
#define GH_  128
#define EG_  544          // 8*N
#define T_   8704         // B*N
#define FLAT_ 4096        // K*16*16
#define FCH_ 16           // f-chunks in lin1 (K-split of 256)

typedef __attribute__((ext_vector_type(8))) _Float16 half8;
typedef __attribute__((ext_vector_type(2))) _Float16 half2v;
typedef __attribute__((ext_vector_type(4))) float   floatx4;
typedef __attribute__((ext_vector_type(2))) float   v2f;

// ---------------------------------------------------------------------------
// K1: per-node conv3x3(SAME)+bias+relu+maxpool2x2 -> pooled[T][4096] fp16.
// One block per node. Accumulators paired vertically (a00,a10),(a01,a11) so
// the inner loop is v_pk_fma_f32 (2 FLOP/instr): 864 pk-FMA/thread vs 1728
// scalar. x window pairs vp[] built once; weights via LDS b128 broadcast.
// ---------------------------------------------------------------------------
__global__ __launch_bounds__(256, 3) void conv_pool_kernel(
    const float* __restrict__ x, const float* __restrict__ conv_w,
    const float* __restrict__ conv_b, _Float16* __restrict__ pooled) {
  const int t = blockIdx.x;
  const int n = t % N_;
  const int tid = threadIdx.x;

  __shared__ float xs[3 * 34 * 34];   // zero-padded [c][34][34]
  __shared__ float wS[K_ * 28];       // [k][28]: 27 weights + bias

  {
    const float* wp = conv_w + (size_t)n * (K_ * 27);
    const float* bp = conv_b + (size_t)n * K_;
    for (int i = tid; i < K_ * 28; i += 256) {
      int k = i / 28, j = i - k * 28;
      wS[i] = (j < 27) ? wp[k * 27 + j] : bp[k];
    }
  }
  // zero only the 1-wide border (interior fully overwritten)
  for (int i = tid; i < 396; i += 256) {
    int c = i / 132, j = i - c * 132;
    int off;
    if (j < 34)       off = j;
    else if (j < 68)  off = 33 * 34 + (j - 34);
    else if (j < 100) off = (j - 68 + 1) * 34;
    else              off = (j - 100 + 1) * 34 + 33;
    xs[c * 1156 + off] = 0.0f;
  }
  const float4* xg = (const float4*)(x + (size_t)t * (C_ * P_ * P_));
  #pragma unroll
  for (int j = 0; j < 3; j++) {
    int i4 = tid + j * 256;
    float4 v = xg[i4];
    int f0 = i4 * 4;
    int c = f0 >> 10, rem = f0 & 1023, y = rem >> 5, xc = rem & 31;
    float* dstp = &xs[c * 1156 + (y + 1) * 34 + xc + 1];
    dstp[0] = v.x; dstp[1] = v.y; dstp[2] = v.z; dstp[3] = v.w;
  }
  __syncthreads();

  const int py = tid >> 4, px = tid & 15;

  float xr[3][4][4];
  #pragma unroll
  for (int c = 0; c < 3; c++)
    #pragma unroll
    for (int r = 0; r < 4; r++)
      #pragma unroll
      for (int cc = 0; cc < 4; cc++)
        xr[c][r][cc] = xs[c * 1156 + (2 * py + r) * 34 + (2 * px + cc)];

  // vertical pairs: vp[c][dy][col] = (row dy, row dy+1) at col
  v2f vp[3][3][4];
  #pragma unroll
  for (int c = 0; c < 3; c++)
    #pragma unroll
    for (int rp = 0; rp < 3; rp++)
      #pragma unroll
      for (int col = 0; col < 4; col++)
        vp[c][rp][col] = (v2f){xr[c][rp][col], xr[c][rp + 1][col]};

  _Float16* outp = pooled + (size_t)t * FLAT_ + py * 16 + px;

  #pragma unroll 2
  for (int k = 0; k < K_; k++) {
    float w[28];
    const float4* wk4 = (const float4*)&wS[k * 28];
    #pragma unroll
    for (int q4 = 0; q4 < 7; q4++) *(float4*)&w[q4 * 4] = wk4[q4];  // broadcast
    float bk = w[27];
    v2f a0 = {bk, bk};   // (conv[r0][c0], conv[r1][c0])
    v2f a1 = {bk, bk};   // (conv[r0][c1], conv[r1][c1])
    #pragma unroll
    for (int c = 0; c < 3; c++)
      #pragma unroll
      for (int dy = 0; dy < 3; dy++)
        #pragma unroll
        for (int dx = 0; dx < 3; dx++) {
          float wsc = w[c * 9 + dy * 3 + dx];
          v2f wv = {wsc, wsc};
          a0 += vp[c][dy][dx]     * wv;
          a1 += vp[c][dy][dx + 1] * wv;
        }
    float m = fmaxf(fmaxf(a0.x, a0.y), fmaxf(a1.x, a1.y));
    m = fmaxf(m, 0.0f);
    outp[k * 256] = (_Float16)m;
  }
}

// ---------------------------------------------------------------------------
// K2: per-type linear via fp16 MFMA 16x16x32, K-step software pipeline:
// next step's 8 global loads issue into regs before this step's MFMAs.
// Grid 68 x 16 f-chunks (K=256), 256 threads.
// ---------------------------------------------------------------------------
__global__ __launch_bounds__(256) void lin1_mfma_kernel(
    const _Float16* __restrict__ pooled, const float* __restrict__ lin1_w,
    float* __restrict__ part) {
  const int n   = blockIdx.x >> 4;
  const int fc  = blockIdx.x & 15;
  const int tid = threadIdx.x;
  const int wave = tid >> 6, lane = tid & 63;
  const int q = lane >> 4, lr = lane & 15;

  __shared__ __align__(16) _Float16 As[128 * 72];
  __shared__ __align__(16) _Float16 Bt[64 * 72];

  floatx4 acc[2][4];
  #pragma unroll
  for (int mt = 0; mt < 2; mt++)
    #pragma unroll
    for (int nt = 0; nt < 4; nt++)
      acc[mt][nt] = (floatx4){0.f, 0.f, 0.f, 0.f};

  const int f_base = fc * 256;
  const float* wbase = lin1_w + (size_t)n * (FLAT_ * FD_);

  uint4  aR[4];
  float4 bR[4];
  // prologue: load step 0
  {
    const int f0 = f_base;
    #pragma unroll
    for (int j = 0; j < 4; j++) {
      int idx = tid + j * 256;
      int r = idx >> 3, ch = idx & 7;
      aR[j] = *(const uint4*)&pooled[(size_t)(r * N_ + n) * FLAT_ + f0 + ch * 8];
    }
    const float* wg = wbase + (size_t)f0 * FD_;
    #pragma unroll
    for (int it = 0; it < 2; it++) {
      int p = tid + it * 256;
      int o0 = (p & 15) * 4, k0 = (p >> 4) * 2;
      const float* wgk = wg + k0 * 64 + o0;
      bR[it * 2]     = *(const float4*)wgk;
      bR[it * 2 + 1] = *(const float4*)(wgk + 64);
    }
  }

  for (int step = 0; step < 4; step++) {
    // LDS writes from regs
    #pragma unroll
    for (int j = 0; j < 4; j++) {
      int idx = tid + j * 256;
      int r = idx >> 3, ch = idx & 7;
      *(uint4*)&As[r * 72 + ch * 8] = aR[j];
    }
    #pragma unroll
    for (int it = 0; it < 2; it++) {
      int p = tid + it * 256;
      int o0 = (p & 15) * 4, k0 = (p >> 4) * 2;
      float4 va = bR[it * 2], vb = bR[it * 2 + 1];
      *(half2v*)&Bt[(o0 + 0) * 72 + k0] = (half2v){(_Float16)va.x, (_Float16)vb.x};
      *(half2v*)&Bt[(o0 + 1) * 72 + k0] = (half2v){(_Float16)va.y, (_Float16)vb.y};
      *(half2v*)&Bt[(o0 + 2) * 72 + k0] = (half2v){(_Float16)va.z, (_Float16)vb.z};
      *(half2v*)&Bt[(o0 + 3) * 72 + k0] = (half2v){(_Float16)va.w, (_Float16)vb.w};
    }
    __syncthreads();

    // prefetch step+1 into regs (overlaps MFMAs below)
    if (step < 3) {
      const int f0 = f_base + (step + 1) * 64;
      #pragma unroll
      for (int j = 0; j < 4; j++) {
        int idx = tid + j * 256;
        int r = idx >> 3, ch = idx & 7;
        aR[j] = *(const uint4*)&pooled[(size_t)(r * N_ + n) * FLAT_ + f0 + ch * 8];
      }
      const float* wg = wbase + (size_t)f0 * FD_;
      #pragma unroll
      for (int it = 0; it < 2; it++) {
        int p = tid + it * 256;
        int o0 = (p & 15) * 4, k0 = (p >> 4) * 2;
        const float* wgk = wg + k0 * 64 + o0;
        bR[it * 2]     = *(const float4*)wgk;
        bR[it * 2 + 1] = *(const float4*)(wgk + 64);
      }
    }

    #pragma unroll
    for (int kh = 0; kh < 2; kh++) {
      half8 af[2], bf[4];
      #pragma unroll
      for (int mt = 0; mt < 2; mt++)
        af[mt] = *(const half8*)&As[(wave * 32 + mt * 16 + lr) * 72 + kh * 32 + q * 8];
      #pragma unroll
      for (int nt = 0; nt < 4; nt++)
        bf[nt] = *(const half8*)&Bt[(nt * 16 + lr) * 72 + kh * 32 + q * 8];
      #pragma unroll
      for (int mt = 0; mt < 2; mt++)
        #pragma unroll
        for (int nt = 0; nt < 4; nt++)
          acc[mt][nt] = __builtin_amdgcn_mfma_f32_16x16x32_f16(
              af[mt], bf[nt], acc[mt][nt], 0, 0, 0);
    }
    __syncthreads();
  }

  float* pb = part + (size_t)fc * T_ * FD_;
  #pragma unroll
  for (int mt = 0; mt < 2; mt++) {
    #pragma unroll
    for (int v = 0; v < 4; v++) {
      int r = wave * 32 + mt * 16 + q * 4 + v;
      size_t base = (size_t)(r * N_ + n) * FD_;
      #pragma unroll
      for (int nt = 0; nt < 4; nt++)
        pb[base + nt * 16 + lr] = acc[mt][nt][v];
    }
  }
}

// ---------------------------------------------------------------------------
// K3: fused tail. One block per graph (128 x 512). feats = relu(sum parts +
// bias) -> LDS; edge aggregation (LDS atomics); GEMM [68,64]@[64,128] + relu
// + mean-pool + MLP head.
// ---------------------------------------------------------------------------
__global__ __launch_bounds__(512) void tail_kernel(
    const float* __restrict__ part, const int* __restrict__ edge_index,
    const float* __restrict__ lin1_b, const float* __restrict__ gcn_w,
    const float* __restrict__ gcn_b, const float* __restrict__ w1,
    const float* __restrict__ b1, const float* __restrict__ w2,
    const float* __restrict__ b2, float* __restrict__ out) {
  const int b = blockIdx.x;
  const int tid = threadIdx.x;

  __shared__ float fS[N_ * 68];      // feats, pitch 68
  __shared__ float aS[N_ * 68];      // aggregated
  __shared__ float wS[FD_ * GH_];    // gcn_w, 32 KB
  __shared__ int   esrcS[EG_], edstS[EG_];
  __shared__ float nrmS[EG_];
  __shared__ int   degS[N_];
  __shared__ float disS[N_];
  __shared__ float gP[4][GH_];
  __shared__ float z1S[64];

  if (tid < N_) degS[tid] = 0;
  const int* srcp = edge_index;
  const int* dstp = edge_index + (B_ * EG_);
  const int e0 = b * EG_, nbase = b * N_;
  for (int e = tid; e < EG_; e += 512) {
    esrcS[e] = srcp[e0 + e] - nbase;
    edstS[e] = dstp[e0 + e] - nbase;
  }
  // feats: sum 16 partials + bias, relu
  for (int idx4 = tid; idx4 < N_ * 16; idx4 += 512) {
    int i  = idx4 >> 4;
    int f4 = (idx4 & 15) * 4;
    int t  = b * N_ + i;
    float4 s = *(const float4*)&lin1_b[i * FD_ + f4];
    #pragma unroll
    for (int fc = 0; fc < FCH_; fc++) {
      float4 v = *(const float4*)&part[((size_t)fc * T_ + t) * FD_ + f4];
      s.x += v.x; s.y += v.y; s.z += v.z; s.w += v.w;
    }
    s.x = fmaxf(s.x, 0.f); s.y = fmaxf(s.y, 0.f);
    s.z = fmaxf(s.z, 0.f); s.w = fmaxf(s.w, 0.f);
    *(float4*)&fS[i * 68 + f4] = s;
  }
  #pragma unroll
  for (int j = 0; j < 4; j++)
    ((float4*)wS)[tid + j * 512] = ((const float4*)gcn_w)[tid + j * 512];
  __syncthreads();

  for (int e = tid; e < EG_; e += 512) atomicAdd(&degS[edstS[e]], 1);
  __syncthreads();
  if (tid < N_) disS[tid] = rsqrtf((float)(degS[tid] + 1));   // +1 self-loop
  __syncthreads();
  for (int e = tid; e < EG_; e += 512)
    nrmS[e] = disS[esrcS[e]] * disS[edstS[e]];
  for (int idx4 = tid; idx4 < N_ * 16; idx4 += 512) {
    int i = idx4 >> 4, f4 = (idx4 & 15) * 4;
    float d2 = disS[i] * disS[i];
    float4 v = *(const float4*)&fS[i * 68 + f4];
    v.x *= d2; v.y *= d2; v.z *= d2; v.w *= d2;
    *(float4*)&aS[i * 68 + f4] = v;
  }
  __syncthreads();
  // edge scatter: one edge per wave-instruction, 64 f per lane-group
  for (int idx = tid; idx < EG_ * FD_; idx += 512) {
    int e = idx >> 6, f = idx & 63;
    atomicAdd(&aS[edstS[e] * 68 + f], nrmS[e] * fS[esrcS[e] * 68 + f]);
  }
  __syncthreads();

  // GEMM + relu + pool: j = out col, ig = row group
  const int j = tid & 127, ig = tid >> 7;
  float wc[64];
  #pragma unroll
  for (int k = 0; k < 64; k++) wc[k] = wS[k * GH_ + j];
  const float bias = gcn_b[j];
  float gsum = 0.f;
  for (int i = ig; i < N_; i += 4) {
    float acc = bias;
    #pragma unroll
    for (int kq = 0; kq < 16; kq++) {
      float4 a = *(const float4*)&aS[i * 68 + kq * 4];   // broadcast
      acc += a.x * wc[kq * 4] + a.y * wc[kq * 4 + 1]
           + a.z * wc[kq * 4 + 2] + a.w * wc[kq * 4 + 3];
    }
    gsum += fmaxf(acc, 0.f);
  }
  gP[ig][j] = gsum;
  __syncthreads();
  if (tid < GH_)
    gP[0][tid] = (gP[0][tid] + gP[1][tid] + gP[2][tid] + gP[3][tid]) * (1.f / 68.f);
  __syncthreads();
  if (tid < 64) {
    float s = b1[tid];
    #pragma unroll 8
    for (int jj = 0; jj < GH_; jj++) s += gP[0][jj] * w1[jj * 64 + tid];
    z1S[tid] = fmaxf(s, 0.f);
  }
  __syncthreads();
  if (tid < 2) {
    float s = b2[tid];
    #pragma unroll 8
    for (int jj = 0; jj < 64; jj++) s += z1S[jj] * w2[jj * 2 + tid];
    out[b * 2 + tid] = s;
  }
}

// ---------------------------------------------------------------------------
extern "C" void kernel_launch(void* const* d_in, const int* in_sizes, int n_in,
                              void* d_out, int out_size, void* d_ws, size_t ws_size,
                              hipStream_t stream) {
  const float* x        = (const float*)d_in[0];
  const int*   edge_idx = (const int*)d_in[1];
  // d_in[2] = batch (layout known: t -> t/N), unused
  const float* conv_w   = (const float*)d_in[3];
  const float* conv_b   = (const float*)d_in[4];
  const float* lin1_w   = (const float*)d_in[5];
  const float* lin1_b   = (const float*)d_in[6];
  const float* gcn_w    = (const float*)d_in[7];
  const float* gcn_b    = (const float*)d_in[8];
  const float* mlp_w1   = (const float*)d_in[9];
  const float* mlp_b1   = (const float*)d_in[10];
  const float* mlp_w2   = (const float*)d_in[11];
  const float* mlp_b2   = (const float*)d_in[12];
  float* outp = (float*)d_out;

  char* wsb = (char*)d_ws;
  _Float16* pooled = (_Float16*)wsb;                               // 71.3 MB
  float* part  = (float*)(wsb + (size_t)T_ * FLAT_ * 2);           // 35.7 MB

  conv_pool_kernel<<<T_, 256, 0, stream>>>(x, conv_w, conv_b, pooled);
  lin1_mfma_kernel<<<N_ * FCH_, 256, 0, stream>>>(pooled, lin1_w, part);
  tail_kernel<<<B_, 512, 0, stream>>>(part, edge_idx, lin1_b, gcn_w, gcn_b,
                                      mlp_w1, mlp_b1, mlp_w2, mlp_b2, outp);
}